// Round 2
// baseline (1420.097 us; speedup 1.0000x reference)
//
#include <hip/hip_runtime.h>

#define DIM 128
#define NLAB 1024
#define MT 64
#define LDK 136   // 128 + 8 pad: keeps 16B alignment, 2-way (free) LDS conflicts

typedef __bf16 bf16x4 __attribute__((ext_vector_type(4)));
typedef __bf16 bf16x8 __attribute__((ext_vector_type(8)));
typedef float  f32x4  __attribute__((ext_vector_type(4)));

// ---------------- CSR build step 1: histogram of dst
__global__ __launch_bounds__(256) void k_hist(
    const int* __restrict__ dst, int* __restrict__ cnt, int nE) {
  int e = blockIdx.x * 256 + threadIdx.x;
  if (e < nE) atomicAdd(&cnt[dst[e]], 1);
}

// ---------------- CSR build step 2: exclusive scan (single block, 1024 thr)
__global__ __launch_bounds__(1024) void k_scan(
    const int* __restrict__ cnt, int* __restrict__ off,
    int* __restrict__ cur, int n) {
  __shared__ int part[1024];
  const int t = threadIdx.x;
  const int per = (n + 1023) >> 10;
  const int start = t * per;
  const int end = min(start + per, n);
  int s = 0;
  for (int i = start; i < end; ++i) s += cnt[i];
  part[t] = s;
  __syncthreads();
  for (int d = 1; d < 1024; d <<= 1) {
    int v = (t >= d) ? part[t - d] : 0;
    __syncthreads();
    part[t] += v;
    __syncthreads();
  }
  int excl = (t == 0) ? 0 : part[t - 1];
  if (t == 1023) off[n] = part[1023];
  for (int i = start; i < end; ++i) {
    int c = cnt[i];          // read before cur write: cur may alias cnt
    off[i] = excl;
    cur[i] = excl;
    excl += c;
  }
}

// ---------------- CSR build step 3: fill bins with src ids (sorted by dst)
__global__ __launch_bounds__(256) void k_binfill(
    const int* __restrict__ src, const int* __restrict__ dst,
    int* __restrict__ cur, int* __restrict__ eidx, int nE) {
  int e = blockIdx.x * 256 + threadIdx.x;
  if (e < nE) {
    int p = atomicAdd(&cur[dst[e]], 1);
    eidx[p] = src[e];
  }
}

// ---------------- gather-aggregate: agg[d,:] = sum_{s in N(d)} h[s,:]
// 32 threads per node (one float4 each), 8 nodes per 256-block, 4-way MLP.
__global__ __launch_bounds__(256) void k_gather(
    const float* __restrict__ h, const int* __restrict__ off,
    const int* __restrict__ eidx, float* __restrict__ agg, int n) {
  int node = blockIdx.x * 8 + (threadIdx.x >> 5);
  if (node >= n) return;
  int c = (threadIdx.x & 31) << 2;  // feature col 0,4,...,124
  int beg = off[node], end = off[node + 1];
  float4 a0 = make_float4(0.f, 0.f, 0.f, 0.f);
  float4 a1 = a0, a2 = a0, a3 = a0;
  int e = beg;
  for (; e + 4 <= end; e += 4) {
    int s0 = eidx[e + 0];
    int s1 = eidx[e + 1];
    int s2 = eidx[e + 2];
    int s3 = eidx[e + 3];
    float4 v0 = *(const float4*)(h + (size_t)s0 * DIM + c);
    float4 v1 = *(const float4*)(h + (size_t)s1 * DIM + c);
    float4 v2 = *(const float4*)(h + (size_t)s2 * DIM + c);
    float4 v3 = *(const float4*)(h + (size_t)s3 * DIM + c);
    a0.x += v0.x; a0.y += v0.y; a0.z += v0.z; a0.w += v0.w;
    a1.x += v1.x; a1.y += v1.y; a1.z += v1.z; a1.w += v1.w;
    a2.x += v2.x; a2.y += v2.y; a2.z += v2.z; a2.w += v2.w;
    a3.x += v3.x; a3.y += v3.y; a3.z += v3.z; a3.w += v3.w;
  }
  for (; e < end; ++e) {
    int s = eidx[e];
    float4 v = *(const float4*)(h + (size_t)s * DIM + c);
    a0.x += v.x; a0.y += v.y; a0.z += v.z; a0.w += v.w;
  }
  a0.x += a1.x + a2.x + a3.x;
  a0.y += a1.y + a2.y + a3.y;
  a0.z += a1.z + a2.z + a3.z;
  a0.w += a1.w + a2.w + a3.w;
  *(float4*)(agg + (size_t)node * DIM + c) = a0;
}

// ---------------- fused conv + residual tile:
// ho = hmid + relu(hmid @ rW + rb),  hmid = relu(((1+eps)hin + agg) @ W + b)
// hmid never leaves registers/LDS.
__device__ __forceinline__ void conv_residual_tile(
    const float* __restrict__ hin, const float* __restrict__ agg, float e1,
    const float* __restrict__ W, const float* __restrict__ bias,
    const float* __restrict__ rW, const float* __restrict__ rbias,
    __bf16 (*As)[LDK], __bf16 (*Bs)[LDK],
    int rowBase, int n, int t, float ho[4][2][4]) {
  // ---- phase A staging: As = bf16((1+eps)*hin + agg), Bs = W
#pragma unroll
  for (int it = 0; it < 8; ++it) {
    int idx = (it * 256 + t) << 2;
    int r = idx >> 7, c = idx & 127;
    int node = rowBase + r;
    float4 a4 = make_float4(0.f, 0.f, 0.f, 0.f);
    float4 g4 = a4;
    if (node < n) {
      a4 = *(const float4*)(hin + (size_t)node * DIM + c);
      g4 = *(const float4*)(agg + (size_t)node * DIM + c);
    }
    bf16x4 v;
    v[0] = (__bf16)(e1 * a4.x + g4.x);
    v[1] = (__bf16)(e1 * a4.y + g4.y);
    v[2] = (__bf16)(e1 * a4.z + g4.z);
    v[3] = (__bf16)(e1 * a4.w + g4.w);
    *(bf16x4*)&As[r][c] = v;
  }
  {
    int nloc = t & 127;
    int kh = (t >> 7) << 6;
#pragma unroll
    for (int kk = 0; kk < 64; ++kk) {
      int k = kh + kk;
      Bs[nloc][k] = (__bf16)W[(size_t)k * DIM + nloc];
    }
  }
  __syncthreads();

  const int wv = t >> 6, lane = t & 63;
  const int quad = lane >> 4, l16 = lane & 15;
  f32x4 acc[4][2];
#pragma unroll
  for (int i = 0; i < 4; ++i) {
    acc[i][0] = f32x4{0.f, 0.f, 0.f, 0.f};
    acc[i][1] = f32x4{0.f, 0.f, 0.f, 0.f};
  }
#pragma unroll
  for (int kc = 0; kc < 4; ++kc) {
    int kb = kc * 32 + quad * 8;
    bf16x8 b0 = *(const bf16x8*)&Bs[wv * 32 + l16][kb];
    bf16x8 b1 = *(const bf16x8*)&Bs[wv * 32 + 16 + l16][kb];
#pragma unroll
    for (int rt = 0; rt < 4; ++rt) {
      bf16x8 a = *(const bf16x8*)&As[rt * 16 + l16][kb];
      acc[rt][0] = __builtin_amdgcn_mfma_f32_16x16x32_bf16(a, b0, acc[rt][0], 0, 0, 0);
      acc[rt][1] = __builtin_amdgcn_mfma_f32_16x16x32_bf16(a, b1, acc[rt][1], 0, 0, 0);
    }
  }

  // hmid in registers: hm[rt][ct][r] for row rt*16+quad*4+r, col wv*32+ct*16+l16
  float hm[4][2][4];
#pragma unroll
  for (int rt = 0; rt < 4; ++rt)
#pragma unroll
    for (int ct = 0; ct < 2; ++ct) {
      float bv = bias[wv * 32 + ct * 16 + l16];
#pragma unroll
      for (int r = 0; r < 4; ++r)
        hm[rt][ct][r] = fmaxf(acc[rt][ct][r] + bv, 0.f);
    }

  __syncthreads();  // all waves done reading As/Bs of phase A

  // ---- phase B staging: As = bf16(hmid) from regs, Bs = rW
#pragma unroll
  for (int rt = 0; rt < 4; ++rt)
#pragma unroll
    for (int ct = 0; ct < 2; ++ct) {
      int col = wv * 32 + ct * 16 + l16;
#pragma unroll
      for (int r = 0; r < 4; ++r)
        As[rt * 16 + quad * 4 + r][col] = (__bf16)hm[rt][ct][r];
    }
  {
    int nloc = t & 127;
    int kh = (t >> 7) << 6;
#pragma unroll
    for (int kk = 0; kk < 64; ++kk) {
      int k = kh + kk;
      Bs[nloc][k] = (__bf16)rW[(size_t)k * DIM + nloc];
    }
  }
  __syncthreads();

#pragma unroll
  for (int i = 0; i < 4; ++i) {
    acc[i][0] = f32x4{0.f, 0.f, 0.f, 0.f};
    acc[i][1] = f32x4{0.f, 0.f, 0.f, 0.f};
  }
#pragma unroll
  for (int kc = 0; kc < 4; ++kc) {
    int kb = kc * 32 + quad * 8;
    bf16x8 b0 = *(const bf16x8*)&Bs[wv * 32 + l16][kb];
    bf16x8 b1 = *(const bf16x8*)&Bs[wv * 32 + 16 + l16][kb];
#pragma unroll
    for (int rt = 0; rt < 4; ++rt) {
      bf16x8 a = *(const bf16x8*)&As[rt * 16 + l16][kb];
      acc[rt][0] = __builtin_amdgcn_mfma_f32_16x16x32_bf16(a, b0, acc[rt][0], 0, 0, 0);
      acc[rt][1] = __builtin_amdgcn_mfma_f32_16x16x32_bf16(a, b1, acc[rt][1], 0, 0, 0);
    }
  }

  // ho = hm + relu(acc + rb)
#pragma unroll
  for (int rt = 0; rt < 4; ++rt)
#pragma unroll
    for (int ct = 0; ct < 2; ++ct) {
      float bv = rbias[wv * 32 + ct * 16 + l16];
#pragma unroll
      for (int r = 0; r < 4; ++r)
        ho[rt][ct][r] = hm[rt][ct][r] + fmaxf(acc[rt][ct][r] + bv, 0.f);
    }
}

// ---------------- layer 1: fused conv+residual -> writes h1 (fp32)
__global__ __launch_bounds__(256) void k_layer1(
    const float* __restrict__ hin, const float* __restrict__ agg,
    const float* __restrict__ epsp, const float* __restrict__ W,
    const float* __restrict__ bias, const float* __restrict__ rW,
    const float* __restrict__ rbias, float* __restrict__ h1, int n) {
  __shared__ __bf16 As[MT][LDK];
  __shared__ __bf16 Bs[DIM][LDK];
  const int t = threadIdx.x;
  const int rowBase = blockIdx.x * MT;
  float ho[4][2][4];
  conv_residual_tile(hin, agg, 1.0f + epsp[0], W, bias, rW, rbias,
                     As, Bs, rowBase, n, t, ho);
  const int wv = t >> 6, lane = t & 63;
  const int quad = lane >> 4, l16 = lane & 15;
#pragma unroll
  for (int rt = 0; rt < 4; ++rt)
#pragma unroll
    for (int ct = 0; ct < 2; ++ct) {
      int ncol = wv * 32 + ct * 16 + l16;
#pragma unroll
      for (int r = 0; r < 4; ++r) {
        int node = rowBase + rt * 16 + quad * 4 + r;
        if (node < n) h1[(size_t)node * DIM + ncol] = ho[rt][ct][r];
      }
    }
}

// ---------------- layer 2 + final head, fused:
// h2 tile stays in regs; As = bf16(0.5*(h1+h2)); loop 8 col-blocks of linW.
__global__ __launch_bounds__(256) void k_layer2f(
    const float* __restrict__ h1, const float* __restrict__ agg,
    const float* __restrict__ epsp, const float* __restrict__ W,
    const float* __restrict__ bias, const float* __restrict__ rW,
    const float* __restrict__ rbias, const float* __restrict__ linW,
    const float* __restrict__ linb, float* __restrict__ out, int n) {
  __shared__ __bf16 As[MT][LDK];
  __shared__ __bf16 Bs[DIM][LDK];
  const int t = threadIdx.x;
  const int rowBase = blockIdx.x * MT;
  float ho[4][2][4];
  conv_residual_tile(h1, agg, 1.0f + epsp[0], W, bias, rW, rbias,
                     As, Bs, rowBase, n, t, ho);
  const int wv = t >> 6, lane = t & 63;
  const int quad = lane >> 4, l16 = lane & 15;

  __syncthreads();  // all waves done reading As/Bs of phase B

  // As = bf16(0.5*(h1 + h2)) -- pooled features
#pragma unroll
  for (int rt = 0; rt < 4; ++rt)
#pragma unroll
    for (int ct = 0; ct < 2; ++ct) {
      int col = wv * 32 + ct * 16 + l16;
#pragma unroll
      for (int r = 0; r < 4; ++r) {
        int lrow = rt * 16 + quad * 4 + r;
        int node = rowBase + lrow;
        float h1v = (node < n) ? h1[(size_t)node * DIM + col] : 0.f;
        As[lrow][col] = (__bf16)(0.5f * (h1v + ho[rt][ct][r]));
      }
    }

  for (int nb = 0; nb < 8; ++nb) {
    int nbase = nb << 7;
    {
      int nloc = t & 127;
      int kh = (t >> 7) << 6;
#pragma unroll
      for (int kk = 0; kk < 64; ++kk) {
        int k = kh + kk;
        Bs[nloc][k] = (__bf16)linW[(size_t)k * NLAB + nbase + nloc];
      }
    }
    __syncthreads();

    f32x4 acc[4][2];
#pragma unroll
    for (int i = 0; i < 4; ++i) {
      acc[i][0] = f32x4{0.f, 0.f, 0.f, 0.f};
      acc[i][1] = f32x4{0.f, 0.f, 0.f, 0.f};
    }
#pragma unroll
    for (int kc = 0; kc < 4; ++kc) {
      int kb = kc * 32 + quad * 8;
      bf16x8 b0 = *(const bf16x8*)&Bs[wv * 32 + l16][kb];
      bf16x8 b1 = *(const bf16x8*)&Bs[wv * 32 + 16 + l16][kb];
#pragma unroll
      for (int rt = 0; rt < 4; ++rt) {
        bf16x8 a = *(const bf16x8*)&As[rt * 16 + l16][kb];
        acc[rt][0] = __builtin_amdgcn_mfma_f32_16x16x32_bf16(a, b0, acc[rt][0], 0, 0, 0);
        acc[rt][1] = __builtin_amdgcn_mfma_f32_16x16x32_bf16(a, b1, acc[rt][1], 0, 0, 0);
      }
    }
#pragma unroll
    for (int rt = 0; rt < 4; ++rt)
#pragma unroll
      for (int ct = 0; ct < 2; ++ct) {
        int ncol = wv * 32 + ct * 16 + l16;
        float bv = linb[nbase + ncol];
#pragma unroll
        for (int r = 0; r < 4; ++r) {
          int node = rowBase + rt * 16 + quad * 4 + r;
          if (node < n)
            out[(size_t)node * NLAB + nbase + ncol] = acc[rt][ct][r] + bv;
        }
      }
    __syncthreads();  // before next Bs overwrite
  }
}

extern "C" void kernel_launch(void* const* d_in, const int* in_sizes, int n_in,
                              void* d_out, int out_size, void* d_ws, size_t ws_size,
                              hipStream_t stream) {
  const float* inputs = (const float*)d_in[0];
  const int*   src    = (const int*)d_in[1];
  const int*   dst    = (const int*)d_in[2];
  const float* eps1   = (const float*)d_in[3];
  const float* W1     = (const float*)d_in[4];
  const float* b1     = (const float*)d_in[5];
  const float* rW1    = (const float*)d_in[6];
  const float* rb1    = (const float*)d_in[7];
  const float* eps2   = (const float*)d_in[8];
  const float* W2     = (const float*)d_in[9];
  const float* b2     = (const float*)d_in[10];
  const float* rW2    = (const float*)d_in[11];
  const float* rb2    = (const float*)d_in[12];
  const float* linW   = (const float*)d_in[13];
  const float* linb   = (const float*)d_in[14];
  float* out = (float*)d_out;

  const int n = in_sizes[0] / DIM;
  const int E = in_sizes[1];
  const size_t bufB = (size_t)n * DIM * sizeof(float);

  // node-feature scratch in d_ws
  float* agg = (float*)d_ws;                       // ws0
  float* h1  = (float*)((char*)d_ws + bufB);       // ws1

  // CSR scratch lives in d_out (dead after gather2; out written by k_layer2f)
  int* eidx = (int*)d_out;          // E ints
  int* off  = eidx + E;             // n+1 ints
  int* cur  = off + (n + 1);        // n ints (doubles as histogram cnt)

  const int rowBlocks = (n + MT - 1) / MT;
  const int eBlocks = (E + 255) / 256;
  const int gBlocks = (n + 7) / 8;

  // ---- build CSR once (shared by both layers)
  hipMemsetAsync(cur, 0, (size_t)n * sizeof(int), stream);
  k_hist<<<eBlocks, 256, 0, stream>>>(dst, cur, E);
  k_scan<<<1, 1024, 0, stream>>>(cur, off, cur, n);
  k_binfill<<<eBlocks, 256, 0, stream>>>(src, dst, cur, eidx, E);

  // ---- layer 1 (fused conv+residual)
  k_gather<<<gBlocks, 256, 0, stream>>>(inputs, off, eidx, agg, n);
  k_layer1<<<rowBlocks, 256, 0, stream>>>(inputs, agg, eps1, W1, b1, rW1, rb1, h1, n);
  // ---- layer 2 + final head (fused conv+residual+head)
  k_gather<<<gBlocks, 256, 0, stream>>>(h1, off, eidx, agg, n);
  k_layer2f<<<rowBlocks, 256, 0, stream>>>(h1, agg, eps2, W2, b2, rW2, rb2,
                                           linW, linb, out, n);
}

// Round 3
// 1313.036 us; speedup vs baseline: 1.0815x; 1.0815x over previous
//
#include <hip/hip_runtime.h>

#define DIM 128
#define NLAB 1024
#define MT 64
#define LDK 136   // 128 + 8 pad: keeps 16B alignment, 2-way (free) LDS conflicts

typedef __bf16 bf16x4 __attribute__((ext_vector_type(4)));
typedef __bf16 bf16x8 __attribute__((ext_vector_type(8)));
typedef float  f32x4  __attribute__((ext_vector_type(4)));

// ---------------- CSR build step 1: histogram of dst
__global__ __launch_bounds__(256) void k_hist(
    const int* __restrict__ dst, int* __restrict__ cnt, int nE) {
  int e = blockIdx.x * 256 + threadIdx.x;
  if (e < nE) atomicAdd(&cnt[dst[e]], 1);
}

// ---------------- CSR build step 2: exclusive scan (single block, 1024 thr)
__global__ __launch_bounds__(1024) void k_scan(
    const int* __restrict__ cnt, int* __restrict__ off,
    int* __restrict__ cur, int n) {
  __shared__ int part[1024];
  const int t = threadIdx.x;
  const int per = (n + 1023) >> 10;
  const int start = t * per;
  const int end = min(start + per, n);
  int s = 0;
  for (int i = start; i < end; ++i) s += cnt[i];
  part[t] = s;
  __syncthreads();
  for (int d = 1; d < 1024; d <<= 1) {
    int v = (t >= d) ? part[t - d] : 0;
    __syncthreads();
    part[t] += v;
    __syncthreads();
  }
  int excl = (t == 0) ? 0 : part[t - 1];
  if (t == 1023) off[n] = part[1023];
  for (int i = start; i < end; ++i) {
    int c = cnt[i];          // read before cur write: cur may alias cnt
    off[i] = excl;
    cur[i] = excl;
    excl += c;
  }
}

// ---------------- CSR build step 3: fill bins with src ids (sorted by dst)
__global__ __launch_bounds__(256) void k_binfill(
    const int* __restrict__ src, const int* __restrict__ dst,
    int* __restrict__ cur, int* __restrict__ eidx, int nE) {
  int e = blockIdx.x * 256 + threadIdx.x;
  if (e < nE) {
    int p = atomicAdd(&cur[dst[e]], 1);
    eidx[p] = src[e];
  }
}

// ---------------- gather-aggregate: agg[d,:] = sum_{s in N(d)} h[s,:]
// 32 threads per node (one float4 each), 8 nodes per 256-block, 4-way MLP.
__global__ __launch_bounds__(256) void k_gather(
    const float* __restrict__ h, const int* __restrict__ off,
    const int* __restrict__ eidx, float* __restrict__ agg, int n) {
  int node = blockIdx.x * 8 + (threadIdx.x >> 5);
  if (node >= n) return;
  int c = (threadIdx.x & 31) << 2;  // feature col 0,4,...,124
  int beg = off[node], end = off[node + 1];
  float4 a0 = make_float4(0.f, 0.f, 0.f, 0.f);
  float4 a1 = a0, a2 = a0, a3 = a0;
  int e = beg;
  for (; e + 4 <= end; e += 4) {
    int s0 = eidx[e + 0];
    int s1 = eidx[e + 1];
    int s2 = eidx[e + 2];
    int s3 = eidx[e + 3];
    float4 v0 = *(const float4*)(h + (size_t)s0 * DIM + c);
    float4 v1 = *(const float4*)(h + (size_t)s1 * DIM + c);
    float4 v2 = *(const float4*)(h + (size_t)s2 * DIM + c);
    float4 v3 = *(const float4*)(h + (size_t)s3 * DIM + c);
    a0.x += v0.x; a0.y += v0.y; a0.z += v0.z; a0.w += v0.w;
    a1.x += v1.x; a1.y += v1.y; a1.z += v1.z; a1.w += v1.w;
    a2.x += v2.x; a2.y += v2.y; a2.z += v2.z; a2.w += v2.w;
    a3.x += v3.x; a3.y += v3.y; a3.z += v3.z; a3.w += v3.w;
  }
  for (; e < end; ++e) {
    int s = eidx[e];
    float4 v = *(const float4*)(h + (size_t)s * DIM + c);
    a0.x += v.x; a0.y += v.y; a0.z += v.z; a0.w += v.w;
  }
  a0.x += a1.x + a2.x + a3.x;
  a0.y += a1.y + a2.y + a3.y;
  a0.z += a1.z + a2.z + a3.z;
  a0.w += a1.w + a2.w + a3.w;
  *(float4*)(agg + (size_t)node * DIM + c) = a0;
}

// ---------------- fused conv + residual tile:
// ho = hmid + relu(hmid @ rW + rb),  hmid = relu(((1+eps)hin + agg) @ W + b)
// hmid never leaves registers/LDS.
__device__ __forceinline__ void conv_residual_tile(
    const float* __restrict__ hin, const float* __restrict__ agg, float e1,
    const float* __restrict__ W, const float* __restrict__ bias,
    const float* __restrict__ rW, const float* __restrict__ rbias,
    __bf16 (*As)[LDK], __bf16 (*Bs)[LDK],
    int rowBase, int n, int t, float ho[4][2][4]) {
  // ---- phase A staging: As = bf16((1+eps)*hin + agg), Bs = W
#pragma unroll
  for (int it = 0; it < 8; ++it) {
    int idx = (it * 256 + t) << 2;
    int r = idx >> 7, c = idx & 127;
    int node = rowBase + r;
    float4 a4 = make_float4(0.f, 0.f, 0.f, 0.f);
    float4 g4 = a4;
    if (node < n) {
      a4 = *(const float4*)(hin + (size_t)node * DIM + c);
      g4 = *(const float4*)(agg + (size_t)node * DIM + c);
    }
    bf16x4 v;
    v[0] = (__bf16)(e1 * a4.x + g4.x);
    v[1] = (__bf16)(e1 * a4.y + g4.y);
    v[2] = (__bf16)(e1 * a4.z + g4.z);
    v[3] = (__bf16)(e1 * a4.w + g4.w);
    *(bf16x4*)&As[r][c] = v;
  }
  {
    int nloc = t & 127;
    int kh = (t >> 7) << 6;
#pragma unroll
    for (int kk = 0; kk < 64; ++kk) {
      int k = kh + kk;
      Bs[nloc][k] = (__bf16)W[(size_t)k * DIM + nloc];
    }
  }
  __syncthreads();

  const int wv = t >> 6, lane = t & 63;
  const int quad = lane >> 4, l16 = lane & 15;
  f32x4 acc[4][2];
#pragma unroll
  for (int i = 0; i < 4; ++i) {
    acc[i][0] = f32x4{0.f, 0.f, 0.f, 0.f};
    acc[i][1] = f32x4{0.f, 0.f, 0.f, 0.f};
  }
#pragma unroll
  for (int kc = 0; kc < 4; ++kc) {
    int kb = kc * 32 + quad * 8;
    bf16x8 b0 = *(const bf16x8*)&Bs[wv * 32 + l16][kb];
    bf16x8 b1 = *(const bf16x8*)&Bs[wv * 32 + 16 + l16][kb];
#pragma unroll
    for (int rt = 0; rt < 4; ++rt) {
      bf16x8 a = *(const bf16x8*)&As[rt * 16 + l16][kb];
      acc[rt][0] = __builtin_amdgcn_mfma_f32_16x16x32_bf16(a, b0, acc[rt][0], 0, 0, 0);
      acc[rt][1] = __builtin_amdgcn_mfma_f32_16x16x32_bf16(a, b1, acc[rt][1], 0, 0, 0);
    }
  }

  // hmid in registers: hm[rt][ct][r] for row rt*16+quad*4+r, col wv*32+ct*16+l16
  float hm[4][2][4];
#pragma unroll
  for (int rt = 0; rt < 4; ++rt)
#pragma unroll
    for (int ct = 0; ct < 2; ++ct) {
      float bv = bias[wv * 32 + ct * 16 + l16];
#pragma unroll
      for (int r = 0; r < 4; ++r)
        hm[rt][ct][r] = fmaxf(acc[rt][ct][r] + bv, 0.f);
    }

  __syncthreads();  // all waves done reading As/Bs of phase A

  // ---- phase B staging: As = bf16(hmid) from regs, Bs = rW
#pragma unroll
  for (int rt = 0; rt < 4; ++rt)
#pragma unroll
    for (int ct = 0; ct < 2; ++ct) {
      int col = wv * 32 + ct * 16 + l16;
#pragma unroll
      for (int r = 0; r < 4; ++r)
        As[rt * 16 + quad * 4 + r][col] = (__bf16)hm[rt][ct][r];
    }
  {
    int nloc = t & 127;
    int kh = (t >> 7) << 6;
#pragma unroll
    for (int kk = 0; kk < 64; ++kk) {
      int k = kh + kk;
      Bs[nloc][k] = (__bf16)rW[(size_t)k * DIM + nloc];
    }
  }
  __syncthreads();

#pragma unroll
  for (int i = 0; i < 4; ++i) {
    acc[i][0] = f32x4{0.f, 0.f, 0.f, 0.f};
    acc[i][1] = f32x4{0.f, 0.f, 0.f, 0.f};
  }
#pragma unroll
  for (int kc = 0; kc < 4; ++kc) {
    int kb = kc * 32 + quad * 8;
    bf16x8 b0 = *(const bf16x8*)&Bs[wv * 32 + l16][kb];
    bf16x8 b1 = *(const bf16x8*)&Bs[wv * 32 + 16 + l16][kb];
#pragma unroll
    for (int rt = 0; rt < 4; ++rt) {
      bf16x8 a = *(const bf16x8*)&As[rt * 16 + l16][kb];
      acc[rt][0] = __builtin_amdgcn_mfma_f32_16x16x32_bf16(a, b0, acc[rt][0], 0, 0, 0);
      acc[rt][1] = __builtin_amdgcn_mfma_f32_16x16x32_bf16(a, b1, acc[rt][1], 0, 0, 0);
    }
  }

  // ho = hm + relu(acc + rb)
#pragma unroll
  for (int rt = 0; rt < 4; ++rt)
#pragma unroll
    for (int ct = 0; ct < 2; ++ct) {
      float bv = rbias[wv * 32 + ct * 16 + l16];
#pragma unroll
      for (int r = 0; r < 4; ++r)
        ho[rt][ct][r] = hm[rt][ct][r] + fmaxf(acc[rt][ct][r] + bv, 0.f);
    }
}

// ---------------- layer 1: fused conv+residual -> writes h1 (fp32)
__global__ __launch_bounds__(256) void k_layer1(
    const float* __restrict__ hin, const float* __restrict__ agg,
    const float* __restrict__ epsp, const float* __restrict__ W,
    const float* __restrict__ bias, const float* __restrict__ rW,
    const float* __restrict__ rbias, float* __restrict__ h1, int n) {
  __shared__ __bf16 As[MT][LDK];
  __shared__ __bf16 Bs[DIM][LDK];
  const int t = threadIdx.x;
  const int rowBase = blockIdx.x * MT;
  float ho[4][2][4];
  conv_residual_tile(hin, agg, 1.0f + epsp[0], W, bias, rW, rbias,
                     As, Bs, rowBase, n, t, ho);
  const int wv = t >> 6, lane = t & 63;
  const int quad = lane >> 4, l16 = lane & 15;
#pragma unroll
  for (int rt = 0; rt < 4; ++rt)
#pragma unroll
    for (int ct = 0; ct < 2; ++ct) {
      int ncol = wv * 32 + ct * 16 + l16;
#pragma unroll
      for (int r = 0; r < 4; ++r) {
        int node = rowBase + rt * 16 + quad * 4 + r;
        if (node < n) h1[(size_t)node * DIM + ncol] = ho[rt][ct][r];
      }
    }
}

// ---------------- layer 2: fused conv+residual -> writes pooled bf16 only
// pooled = bf16(0.5*(h1 + h2)); h2 fp32 never touches global.
__global__ __launch_bounds__(256) void k_layer2(
    const float* __restrict__ h1, const float* __restrict__ agg,
    const float* __restrict__ epsp, const float* __restrict__ W,
    const float* __restrict__ bias, const float* __restrict__ rW,
    const float* __restrict__ rbias, __bf16* __restrict__ pooled, int n) {
  __shared__ __bf16 As[MT][LDK];
  __shared__ __bf16 Bs[DIM][LDK];
  const int t = threadIdx.x;
  const int rowBase = blockIdx.x * MT;
  float ho[4][2][4];
  conv_residual_tile(h1, agg, 1.0f + epsp[0], W, bias, rW, rbias,
                     As, Bs, rowBase, n, t, ho);
  const int wv = t >> 6, lane = t & 63;
  const int quad = lane >> 4, l16 = lane & 15;
#pragma unroll
  for (int rt = 0; rt < 4; ++rt)
#pragma unroll
    for (int ct = 0; ct < 2; ++ct) {
      int col = wv * 32 + ct * 16 + l16;
#pragma unroll
      for (int r = 0; r < 4; ++r) {
        int node = rowBase + rt * 16 + quad * 4 + r;
        if (node < n) {
          float h1v = h1[(size_t)node * DIM + col];
          pooled[(size_t)node * DIM + col] =
              (__bf16)(0.5f * (h1v + ho[rt][ct][r]));
        }
      }
    }
}

// ---------------- final head: out = pooled @ linW + linb, 2D grid (rows x 8)
__global__ __launch_bounds__(256) void k_final_p(
    const __bf16* __restrict__ pooled, const float* __restrict__ W,
    const float* __restrict__ bias, float* __restrict__ out, int n) {
  __shared__ __bf16 As[MT][LDK];
  __shared__ __bf16 Bs[DIM][LDK];
  const int t = threadIdx.x;
  const int rowBase = blockIdx.x * MT;
  const int nb = blockIdx.y << 7;

  // As staging: direct bf16x8 vector loads from pooled (no conversion VALU)
#pragma unroll
  for (int it = 0; it < 4; ++it) {
    int idx = (it * 256 + t) << 3;
    int r = idx >> 7, c = idx & 127;
    int node = rowBase + r;
    bf16x8 v;
#pragma unroll
    for (int j = 0; j < 8; ++j) v[j] = (__bf16)0.f;
    if (node < n) v = *(const bf16x8*)(pooled + (size_t)node * DIM + c);
    *(bf16x8*)&As[r][c] = v;
  }
  {
    int nloc = t & 127;
    int kh = (t >> 7) << 6;
#pragma unroll
    for (int kk = 0; kk < 64; ++kk) {
      int k = kh + kk;
      Bs[nloc][k] = (__bf16)W[(size_t)k * NLAB + nb + nloc];
    }
  }
  __syncthreads();

  const int wv = t >> 6, lane = t & 63;
  const int quad = lane >> 4, l16 = lane & 15;
  f32x4 acc[4][2];
#pragma unroll
  for (int i = 0; i < 4; ++i) {
    acc[i][0] = f32x4{0.f, 0.f, 0.f, 0.f};
    acc[i][1] = f32x4{0.f, 0.f, 0.f, 0.f};
  }

#pragma unroll
  for (int kc = 0; kc < 4; ++kc) {
    int kb = kc * 32 + quad * 8;
    bf16x8 b0 = *(const bf16x8*)&Bs[wv * 32 + l16][kb];
    bf16x8 b1 = *(const bf16x8*)&Bs[wv * 32 + 16 + l16][kb];
#pragma unroll
    for (int rt = 0; rt < 4; ++rt) {
      bf16x8 a = *(const bf16x8*)&As[rt * 16 + l16][kb];
      acc[rt][0] = __builtin_amdgcn_mfma_f32_16x16x32_bf16(a, b0, acc[rt][0], 0, 0, 0);
      acc[rt][1] = __builtin_amdgcn_mfma_f32_16x16x32_bf16(a, b1, acc[rt][1], 0, 0, 0);
    }
  }

#pragma unroll
  for (int rt = 0; rt < 4; ++rt)
#pragma unroll
    for (int ct = 0; ct < 2; ++ct) {
      int ncol = wv * 32 + ct * 16 + l16;
      float bv = bias[nb + ncol];
#pragma unroll
      for (int r = 0; r < 4; ++r) {
        int node = rowBase + rt * 16 + quad * 4 + r;
        if (node < n)
          out[(size_t)node * NLAB + nb + ncol] = acc[rt][ct][r] + bv;
      }
    }
}

extern "C" void kernel_launch(void* const* d_in, const int* in_sizes, int n_in,
                              void* d_out, int out_size, void* d_ws, size_t ws_size,
                              hipStream_t stream) {
  const float* inputs = (const float*)d_in[0];
  const int*   src    = (const int*)d_in[1];
  const int*   dst    = (const int*)d_in[2];
  const float* eps1   = (const float*)d_in[3];
  const float* W1     = (const float*)d_in[4];
  const float* b1     = (const float*)d_in[5];
  const float* rW1    = (const float*)d_in[6];
  const float* rb1    = (const float*)d_in[7];
  const float* eps2   = (const float*)d_in[8];
  const float* W2     = (const float*)d_in[9];
  const float* b2     = (const float*)d_in[10];
  const float* rW2    = (const float*)d_in[11];
  const float* rb2    = (const float*)d_in[12];
  const float* linW   = (const float*)d_in[13];
  const float* linb   = (const float*)d_in[14];
  float* out = (float*)d_out;

  const int n = in_sizes[0] / DIM;
  const int E = in_sizes[1];
  const size_t bufB = (size_t)n * DIM * sizeof(float);

  // node-feature scratch in d_ws
  float*  agg    = (float*)d_ws;                    // ws0
  float*  h1     = (float*)((char*)d_ws + bufB);    // ws1
  __bf16* pooled = (__bf16*)((char*)d_ws + 2 * bufB); // ws2 (bf16, 25.6 MB)

  // CSR scratch lives in d_out (dead after gather2; out written by k_final_p)
  int* eidx = (int*)d_out;          // E ints
  int* off  = eidx + E;             // n+1 ints
  int* cur  = off + (n + 1);        // n ints (doubles as histogram cnt)

  const int rowBlocks = (n + MT - 1) / MT;
  const int eBlocks = (E + 255) / 256;
  const int gBlocks = (n + 7) / 8;
  dim3 fgrid(rowBlocks, NLAB / DIM);

  // ---- build CSR once (shared by both layers)
  hipMemsetAsync(cur, 0, (size_t)n * sizeof(int), stream);
  k_hist<<<eBlocks, 256, 0, stream>>>(dst, cur, E);
  k_scan<<<1, 1024, 0, stream>>>(cur, off, cur, n);
  k_binfill<<<eBlocks, 256, 0, stream>>>(src, dst, cur, eidx, E);

  // ---- layer 1 (fused conv+residual)
  k_gather<<<gBlocks, 256, 0, stream>>>(inputs, off, eidx, agg, n);
  k_layer1<<<rowBlocks, 256, 0, stream>>>(inputs, agg, eps1, W1, b1, rW1, rb1, h1, n);
  // ---- layer 2 (fused conv+residual, emits pooled bf16 directly)
  k_gather<<<gBlocks, 256, 0, stream>>>(h1, off, eidx, agg, n);
  k_layer2<<<rowBlocks, 256, 0, stream>>>(h1, agg, eps2, W2, b2, rW2, rb2,
                                          pooled, n);
  // ---- final head (2D grid, reads tiny bf16 pooled; overwrites CSR scratch)
  k_final_p<<<fgrid, 256, 0, stream>>>(pooled, linW, linb, out, n);
}

// Round 4
// 1156.491 us; speedup vs baseline: 1.2279x; 1.1354x over previous
//
#include <hip/hip_runtime.h>

#define DIM 128
#define NLAB 1024
#define MT 64
#define LDK 136   // 128 + 8 pad: keeps 16B alignment, 2-way (free) LDS conflicts

typedef __bf16 bf16x4 __attribute__((ext_vector_type(4)));
typedef __bf16 bf16x8 __attribute__((ext_vector_type(8)));
typedef float  f32x4  __attribute__((ext_vector_type(4)));

// ---------------- CSR build step 1: histogram of dst
__global__ __launch_bounds__(256) void k_hist(
    const int* __restrict__ dst, int* __restrict__ cnt, int nE) {
  int e = blockIdx.x * 256 + threadIdx.x;
  if (e < nE) atomicAdd(&cnt[dst[e]], 1);
}

// ---------------- CSR build step 2: exclusive scan (single block, 1024 thr)
__global__ __launch_bounds__(1024) void k_scan(
    const int* __restrict__ cnt, int* __restrict__ off,
    int* __restrict__ cur, int n) {
  __shared__ int part[1024];
  const int t = threadIdx.x;
  const int per = (n + 1023) >> 10;
  const int start = t * per;
  const int end = min(start + per, n);
  int s = 0;
  for (int i = start; i < end; ++i) s += cnt[i];
  part[t] = s;
  __syncthreads();
  for (int d = 1; d < 1024; d <<= 1) {
    int v = (t >= d) ? part[t - d] : 0;
    __syncthreads();
    part[t] += v;
    __syncthreads();
  }
  int excl = (t == 0) ? 0 : part[t - 1];
  if (t == 1023) off[n] = part[1023];
  for (int i = start; i < end; ++i) {
    int c = cnt[i];          // read before cur write: cur may alias cnt
    off[i] = excl;
    cur[i] = excl;
    excl += c;
  }
}

// ---------------- CSR build step 3: fill bins with src ids (sorted by dst)
__global__ __launch_bounds__(256) void k_binfill(
    const int* __restrict__ src, const int* __restrict__ dst,
    int* __restrict__ cur, int* __restrict__ eidx, int nE) {
  int e = blockIdx.x * 256 + threadIdx.x;
  if (e < nE) {
    int p = atomicAdd(&cur[dst[e]], 1);
    eidx[p] = src[e];
  }
}

// ---------------- weight preconvert: fp32 [k][n] -> bf16 [n][k] (n-major)
// W1/rW1/W2/rW2: 128x128 each; linW: 128x1024.
__global__ __launch_bounds__(256) void k_cvt_w(
    const float* __restrict__ W1, const float* __restrict__ rW1,
    const float* __restrict__ W2, const float* __restrict__ rW2,
    const float* __restrict__ linW,
    __bf16* __restrict__ W1b, __bf16* __restrict__ rW1b,
    __bf16* __restrict__ W2b, __bf16* __restrict__ rW2b,
    __bf16* __restrict__ linWb) {
  int tid = blockIdx.x * 256 + threadIdx.x;
  if (tid < 65536) {
    int m = tid >> 14, i = tid & 16383;
    int nn = i >> 7, k = i & 127;
    const float* S = (m == 0) ? W1 : (m == 1) ? rW1 : (m == 2) ? W2 : rW2;
    __bf16* D = (m == 0) ? W1b : (m == 1) ? rW1b : (m == 2) ? W2b : rW2b;
    D[nn * DIM + k] = (__bf16)S[(size_t)k * DIM + nn];
  } else if (tid < 196608) {
    int i = tid - 65536;
    int nn = i >> 7, k = i & 127;
    linWb[(size_t)nn * DIM + k] = (__bf16)linW[(size_t)k * NLAB + nn];
  }
}

// ---------------- inputs fp32 -> bf16 (8 elems/thread)
__global__ __launch_bounds__(256) void k_cvt_in(
    const float* __restrict__ x, __bf16* __restrict__ y, int n) {
  size_t i = (size_t)blockIdx.x * 256 + threadIdx.x;
  if (i >= (size_t)n * 16) return;
  float4 a = ((const float4*)x)[i * 2];
  float4 b = ((const float4*)x)[i * 2 + 1];
  bf16x8 v;
  v[0] = (__bf16)a.x; v[1] = (__bf16)a.y; v[2] = (__bf16)a.z; v[3] = (__bf16)a.w;
  v[4] = (__bf16)b.x; v[5] = (__bf16)b.y; v[6] = (__bf16)b.z; v[7] = (__bf16)b.w;
  ((bf16x8*)y)[i] = v;
}

// ---------------- gather-aggregate over bf16 features:
// agg[d,:] = sum_{s in N(d)} h[s,:] (fp32 accumulate)
// 16 threads per node (bf16x8 = 16B each), 16 nodes per 256-block, 4-way MLP.
__global__ __launch_bounds__(256) void k_gather_b(
    const __bf16* __restrict__ h, const int* __restrict__ off,
    const int* __restrict__ eidx, float* __restrict__ agg, int n) {
  int node = blockIdx.x * 16 + (threadIdx.x >> 4);
  if (node >= n) return;
  int c = (threadIdx.x & 15) << 3;  // feature col 0,8,...,120
  int beg = off[node], end = off[node + 1];
  float a0[8] = {0.f, 0.f, 0.f, 0.f, 0.f, 0.f, 0.f, 0.f};
  float a1[8] = {0.f, 0.f, 0.f, 0.f, 0.f, 0.f, 0.f, 0.f};
  float a2[8] = {0.f, 0.f, 0.f, 0.f, 0.f, 0.f, 0.f, 0.f};
  float a3[8] = {0.f, 0.f, 0.f, 0.f, 0.f, 0.f, 0.f, 0.f};
  int e = beg;
  for (; e + 4 <= end; e += 4) {
    int s0 = eidx[e + 0];
    int s1 = eidx[e + 1];
    int s2 = eidx[e + 2];
    int s3 = eidx[e + 3];
    bf16x8 v0 = *(const bf16x8*)(h + (size_t)s0 * DIM + c);
    bf16x8 v1 = *(const bf16x8*)(h + (size_t)s1 * DIM + c);
    bf16x8 v2 = *(const bf16x8*)(h + (size_t)s2 * DIM + c);
    bf16x8 v3 = *(const bf16x8*)(h + (size_t)s3 * DIM + c);
#pragma unroll
    for (int j = 0; j < 8; ++j) {
      a0[j] += (float)v0[j];
      a1[j] += (float)v1[j];
      a2[j] += (float)v2[j];
      a3[j] += (float)v3[j];
    }
  }
  for (; e < end; ++e) {
    int s = eidx[e];
    bf16x8 v = *(const bf16x8*)(h + (size_t)s * DIM + c);
#pragma unroll
    for (int j = 0; j < 8; ++j) a0[j] += (float)v[j];
  }
  float4 o0, o1;
  o0.x = a0[0] + a1[0] + a2[0] + a3[0];
  o0.y = a0[1] + a1[1] + a2[1] + a3[1];
  o0.z = a0[2] + a1[2] + a2[2] + a3[2];
  o0.w = a0[3] + a1[3] + a2[3] + a3[3];
  o1.x = a0[4] + a1[4] + a2[4] + a3[4];
  o1.y = a0[5] + a1[5] + a2[5] + a3[5];
  o1.z = a0[6] + a1[6] + a2[6] + a3[6];
  o1.w = a0[7] + a1[7] + a2[7] + a3[7];
  *(float4*)(agg + (size_t)node * DIM + c) = o0;
  *(float4*)(agg + (size_t)node * DIM + c + 4) = o1;
}

// ---------------- fused conv + residual tile (B direct-from-global bf16):
// ho = hmid + relu(hmid @ rW + rb),  hmid = relu(((1+eps)hin + agg) @ W + b)
// Wb/rWb are bf16 n-major [128][128]; fragments loaded straight from L2.
__device__ __forceinline__ void conv_residual_tile(
    const __bf16* __restrict__ hinb, const float* __restrict__ agg, float e1,
    const __bf16* __restrict__ Wb, const float* __restrict__ bias,
    const __bf16* __restrict__ rWb, const float* __restrict__ rbias,
    __bf16 (*As)[LDK], int rowBase, int n, int t, float ho[4][2][4]) {
  // ---- phase A staging: As = bf16((1+eps)*hin + agg)
#pragma unroll
  for (int it = 0; it < 4; ++it) {
    int idx = (it * 256 + t) << 3;
    int r = idx >> 7, c = idx & 127;
    int node = rowBase + r;
    bf16x8 v;
#pragma unroll
    for (int j = 0; j < 8; ++j) v[j] = (__bf16)0.f;
    if (node < n) {
      bf16x8 hv = *(const bf16x8*)(hinb + (size_t)node * DIM + c);
      float4 g0 = *(const float4*)(agg + (size_t)node * DIM + c);
      float4 g1 = *(const float4*)(agg + (size_t)node * DIM + c + 4);
      v[0] = (__bf16)(e1 * (float)hv[0] + g0.x);
      v[1] = (__bf16)(e1 * (float)hv[1] + g0.y);
      v[2] = (__bf16)(e1 * (float)hv[2] + g0.z);
      v[3] = (__bf16)(e1 * (float)hv[3] + g0.w);
      v[4] = (__bf16)(e1 * (float)hv[4] + g1.x);
      v[5] = (__bf16)(e1 * (float)hv[5] + g1.y);
      v[6] = (__bf16)(e1 * (float)hv[6] + g1.z);
      v[7] = (__bf16)(e1 * (float)hv[7] + g1.w);
    }
    *(bf16x8*)&As[r][c] = v;
  }
  __syncthreads();

  const int wv = t >> 6, lane = t & 63;
  const int quad = lane >> 4, l16 = lane & 15;
  const __bf16* B0p = Wb + (size_t)(wv * 32 + l16) * DIM;
  const __bf16* B1p = Wb + (size_t)(wv * 32 + 16 + l16) * DIM;

  f32x4 acc[4][2];
#pragma unroll
  for (int i = 0; i < 4; ++i) {
    acc[i][0] = f32x4{0.f, 0.f, 0.f, 0.f};
    acc[i][1] = f32x4{0.f, 0.f, 0.f, 0.f};
  }
#pragma unroll
  for (int kc = 0; kc < 4; ++kc) {
    int kb = kc * 32 + quad * 8;
    bf16x8 b0 = *(const bf16x8*)(B0p + kb);
    bf16x8 b1 = *(const bf16x8*)(B1p + kb);
#pragma unroll
    for (int rt = 0; rt < 4; ++rt) {
      bf16x8 a = *(const bf16x8*)&As[rt * 16 + l16][kb];
      acc[rt][0] = __builtin_amdgcn_mfma_f32_16x16x32_bf16(a, b0, acc[rt][0], 0, 0, 0);
      acc[rt][1] = __builtin_amdgcn_mfma_f32_16x16x32_bf16(a, b1, acc[rt][1], 0, 0, 0);
    }
  }

  // hmid in registers
  float hm[4][2][4];
#pragma unroll
  for (int rt = 0; rt < 4; ++rt)
#pragma unroll
    for (int ct = 0; ct < 2; ++ct) {
      float bv = bias[wv * 32 + ct * 16 + l16];
#pragma unroll
      for (int r = 0; r < 4; ++r)
        hm[rt][ct][r] = fmaxf(acc[rt][ct][r] + bv, 0.f);
    }

  __syncthreads();  // all waves done reading phase-A As

  // ---- phase B staging: As = bf16(hmid) from regs
#pragma unroll
  for (int rt = 0; rt < 4; ++rt)
#pragma unroll
    for (int ct = 0; ct < 2; ++ct) {
      int col = wv * 32 + ct * 16 + l16;
#pragma unroll
      for (int r = 0; r < 4; ++r)
        As[rt * 16 + quad * 4 + r][col] = (__bf16)hm[rt][ct][r];
    }
  __syncthreads();

  const __bf16* R0p = rWb + (size_t)(wv * 32 + l16) * DIM;
  const __bf16* R1p = rWb + (size_t)(wv * 32 + 16 + l16) * DIM;
#pragma unroll
  for (int i = 0; i < 4; ++i) {
    acc[i][0] = f32x4{0.f, 0.f, 0.f, 0.f};
    acc[i][1] = f32x4{0.f, 0.f, 0.f, 0.f};
  }
#pragma unroll
  for (int kc = 0; kc < 4; ++kc) {
    int kb = kc * 32 + quad * 8;
    bf16x8 b0 = *(const bf16x8*)(R0p + kb);
    bf16x8 b1 = *(const bf16x8*)(R1p + kb);
#pragma unroll
    for (int rt = 0; rt < 4; ++rt) {
      bf16x8 a = *(const bf16x8*)&As[rt * 16 + l16][kb];
      acc[rt][0] = __builtin_amdgcn_mfma_f32_16x16x32_bf16(a, b0, acc[rt][0], 0, 0, 0);
      acc[rt][1] = __builtin_amdgcn_mfma_f32_16x16x32_bf16(a, b1, acc[rt][1], 0, 0, 0);
    }
  }

  // ho = hm + relu(acc + rb)
#pragma unroll
  for (int rt = 0; rt < 4; ++rt)
#pragma unroll
    for (int ct = 0; ct < 2; ++ct) {
      float bv = rbias[wv * 32 + ct * 16 + l16];
#pragma unroll
      for (int r = 0; r < 4; ++r)
        ho[rt][ct][r] = hm[rt][ct][r] + fmaxf(acc[rt][ct][r] + bv, 0.f);
    }
}

// ---------------- layer 1: fused conv+residual -> writes h1 (bf16)
__global__ __launch_bounds__(256, 3) void k_layer1(
    const __bf16* __restrict__ hinb, const float* __restrict__ agg,
    const float* __restrict__ epsp, const __bf16* __restrict__ Wb,
    const float* __restrict__ bias, const __bf16* __restrict__ rWb,
    const float* __restrict__ rbias, __bf16* __restrict__ h1b, int n) {
  __shared__ __bf16 As[MT][LDK];
  const int t = threadIdx.x;
  const int rowBase = blockIdx.x * MT;
  float ho[4][2][4];
  conv_residual_tile(hinb, agg, 1.0f + epsp[0], Wb, bias, rWb, rbias,
                     As, rowBase, n, t, ho);
  const int wv = t >> 6, lane = t & 63;
  const int quad = lane >> 4, l16 = lane & 15;
#pragma unroll
  for (int rt = 0; rt < 4; ++rt)
#pragma unroll
    for (int ct = 0; ct < 2; ++ct) {
      int ncol = wv * 32 + ct * 16 + l16;
#pragma unroll
      for (int r = 0; r < 4; ++r) {
        int node = rowBase + rt * 16 + quad * 4 + r;
        if (node < n) h1b[(size_t)node * DIM + ncol] = (__bf16)ho[rt][ct][r];
      }
    }
}

// ---------------- layer 2: fused conv+residual -> writes pooled bf16 only
__global__ __launch_bounds__(256, 3) void k_layer2(
    const __bf16* __restrict__ h1b, const float* __restrict__ agg,
    const float* __restrict__ epsp, const __bf16* __restrict__ Wb,
    const float* __restrict__ bias, const __bf16* __restrict__ rWb,
    const float* __restrict__ rbias, __bf16* __restrict__ pooled, int n) {
  __shared__ __bf16 As[MT][LDK];
  const int t = threadIdx.x;
  const int rowBase = blockIdx.x * MT;
  float ho[4][2][4];
  conv_residual_tile(h1b, agg, 1.0f + epsp[0], Wb, bias, rWb, rbias,
                     As, rowBase, n, t, ho);
  const int wv = t >> 6, lane = t & 63;
  const int quad = lane >> 4, l16 = lane & 15;
#pragma unroll
  for (int rt = 0; rt < 4; ++rt)
#pragma unroll
    for (int ct = 0; ct < 2; ++ct) {
      int col = wv * 32 + ct * 16 + l16;
#pragma unroll
      for (int r = 0; r < 4; ++r) {
        int node = rowBase + rt * 16 + quad * 4 + r;
        if (node < n) {
          float h1v = (float)h1b[(size_t)node * DIM + col];
          pooled[(size_t)node * DIM + col] =
              (__bf16)(0.5f * (h1v + ho[rt][ct][r]));
        }
      }
    }
}

// ---------------- final head: out = pooled @ linW + linb, 2D grid (rows x 8)
// B direct-from-global bf16; LDS = As only -> 4 blocks/CU.
__global__ __launch_bounds__(256, 4) void k_final_p(
    const __bf16* __restrict__ pooled, const __bf16* __restrict__ Wb,
    const float* __restrict__ bias, float* __restrict__ out, int n) {
  __shared__ __bf16 As[MT][LDK];
  const int t = threadIdx.x;
  const int rowBase = blockIdx.x * MT;
  const int nb = blockIdx.y << 7;

#pragma unroll
  for (int it = 0; it < 4; ++it) {
    int idx = (it * 256 + t) << 3;
    int r = idx >> 7, c = idx & 127;
    int node = rowBase + r;
    bf16x8 v;
#pragma unroll
    for (int j = 0; j < 8; ++j) v[j] = (__bf16)0.f;
    if (node < n) v = *(const bf16x8*)(pooled + (size_t)node * DIM + c);
    *(bf16x8*)&As[r][c] = v;
  }
  __syncthreads();

  const int wv = t >> 6, lane = t & 63;
  const int quad = lane >> 4, l16 = lane & 15;
  const __bf16* B0p = Wb + (size_t)(nb + wv * 32 + l16) * DIM;
  const __bf16* B1p = Wb + (size_t)(nb + wv * 32 + 16 + l16) * DIM;

  f32x4 acc[4][2];
#pragma unroll
  for (int i = 0; i < 4; ++i) {
    acc[i][0] = f32x4{0.f, 0.f, 0.f, 0.f};
    acc[i][1] = f32x4{0.f, 0.f, 0.f, 0.f};
  }
#pragma unroll
  for (int kc = 0; kc < 4; ++kc) {
    int kb = kc * 32 + quad * 8;
    bf16x8 b0 = *(const bf16x8*)(B0p + kb);
    bf16x8 b1 = *(const bf16x8*)(B1p + kb);
#pragma unroll
    for (int rt = 0; rt < 4; ++rt) {
      bf16x8 a = *(const bf16x8*)&As[rt * 16 + l16][kb];
      acc[rt][0] = __builtin_amdgcn_mfma_f32_16x16x32_bf16(a, b0, acc[rt][0], 0, 0, 0);
      acc[rt][1] = __builtin_amdgcn_mfma_f32_16x16x32_bf16(a, b1, acc[rt][1], 0, 0, 0);
    }
  }

#pragma unroll
  for (int rt = 0; rt < 4; ++rt)
#pragma unroll
    for (int ct = 0; ct < 2; ++ct) {
      int ncol = wv * 32 + ct * 16 + l16;
      float bv = bias[nb + ncol];
#pragma unroll
      for (int r = 0; r < 4; ++r) {
        int node = rowBase + rt * 16 + quad * 4 + r;
        if (node < n)
          out[(size_t)node * NLAB + nb + ncol] = acc[rt][ct][r] + bv;
      }
    }
}

extern "C" void kernel_launch(void* const* d_in, const int* in_sizes, int n_in,
                              void* d_out, int out_size, void* d_ws, size_t ws_size,
                              hipStream_t stream) {
  const float* inputs = (const float*)d_in[0];
  const int*   src    = (const int*)d_in[1];
  const int*   dst    = (const int*)d_in[2];
  const float* eps1   = (const float*)d_in[3];
  const float* W1     = (const float*)d_in[4];
  const float* b1     = (const float*)d_in[5];
  const float* rW1    = (const float*)d_in[6];
  const float* rb1    = (const float*)d_in[7];
  const float* eps2   = (const float*)d_in[8];
  const float* W2     = (const float*)d_in[9];
  const float* b2     = (const float*)d_in[10];
  const float* rW2    = (const float*)d_in[11];
  const float* rb2    = (const float*)d_in[12];
  const float* linW   = (const float*)d_in[13];
  const float* linb   = (const float*)d_in[14];
  float* out = (float*)d_out;

  const int n = in_sizes[0] / DIM;
  const int E = in_sizes[1];
  const size_t bufB = (size_t)n * DIM * sizeof(float);   // fp32 node buffer
  const size_t halfB = bufB >> 1;                        // bf16 node buffer

  // workspace layout (~128.5 MB)
  char* wp = (char*)d_ws;
  float*  agg    = (float*)wp;   wp += bufB;
  __bf16* hb0    = (__bf16*)wp;  wp += halfB;
  __bf16* h1b    = (__bf16*)wp;  wp += halfB;
  __bf16* pooled = (__bf16*)wp;  wp += halfB;
  __bf16* W1b    = (__bf16*)wp;  wp += 32768;
  __bf16* rW1b   = (__bf16*)wp;  wp += 32768;
  __bf16* W2b    = (__bf16*)wp;  wp += 32768;
  __bf16* rW2b   = (__bf16*)wp;  wp += 32768;
  __bf16* linWb  = (__bf16*)wp;

  // CSR scratch lives in d_out (dead after gather2; out written by k_final_p)
  int* eidx = (int*)d_out;          // E ints
  int* off  = eidx + E;             // n+1 ints
  int* cur  = off + (n + 1);        // n ints (doubles as histogram cnt)

  const int rowBlocks = (n + MT - 1) / MT;
  const int eBlocks = (E + 255) / 256;
  const int gBlocks = (n + 15) / 16;
  const int cBlocks = (n * 16 + 255) / 256;
  dim3 fgrid(rowBlocks, NLAB / DIM);

  // ---- precision/layout preconversion (weights + inputs)
  k_cvt_w<<<768, 256, 0, stream>>>(W1, rW1, W2, rW2, linW,
                                   W1b, rW1b, W2b, rW2b, linWb);
  k_cvt_in<<<cBlocks, 256, 0, stream>>>(inputs, hb0, n);

  // ---- build CSR once (shared by both layers)
  hipMemsetAsync(cur, 0, (size_t)n * sizeof(int), stream);
  k_hist<<<eBlocks, 256, 0, stream>>>(dst, cur, E);
  k_scan<<<1, 1024, 0, stream>>>(cur, off, cur, n);
  k_binfill<<<eBlocks, 256, 0, stream>>>(src, dst, cur, eidx, E);

  // ---- layer 1 (fused conv+residual, bf16 storage)
  k_gather_b<<<gBlocks, 256, 0, stream>>>(hb0, off, eidx, agg, n);
  k_layer1<<<rowBlocks, 256, 0, stream>>>(hb0, agg, eps1, W1b, b1, rW1b, rb1,
                                          h1b, n);
  // ---- layer 2 (fused conv+residual, emits pooled bf16 directly)
  k_gather_b<<<gBlocks, 256, 0, stream>>>(h1b, off, eidx, agg, n);
  k_layer2<<<rowBlocks, 256, 0, stream>>>(h1b, agg, eps2, W2b, b2, rW2b, rb2,
                                          pooled, n);
  // ---- final head (2D grid; overwrites CSR scratch in d_out)
  k_final_p<<<fgrid, 256, 0, stream>>>(pooled, linWb, linb, out, n);
}